// Round 3
// baseline (6155.933 us; speedup 1.0000x reference)
//
#include <hip/hip_runtime.h>

// Problem constants (BasicBlock: N=32, C=256, H=W=56, 3x3 convs, stride 1, pad 1)
// ALL tensors are float32 (per reference setup_inputs / output dtype).
#define N_  32
#define C_  256
#define H_  56
#define W_  56
#define HW_ (H_ * W_)       // 3136
#define NHW_ (N_ * HW_)     // 100352
#define PW_ 58              // padded row width (W + 2)
#define CI_CHUNK 64         // input channels staged per LDS pass (fp32 -> 44.5 KB)

// Direct 3x3 conv, pad 1, stride 1, fp32. Block = one (n, h) output row x 64
// output channels. tid&63 = co_local (per-lane weight stream; LDS x reads are
// wave-uniform broadcasts). tid>>6 = w-group; each thread computes 14 pixels.
// mask[co] folded into the epilogue (structured pruning).
extern "C" __global__ __launch_bounds__(256) void BasicBlock_4355096838467_kernel(
    const float* __restrict__ in,
    const float* __restrict__ wt,    // [C_out, C_in, 3, 3]
    const float* __restrict__ mask,  // [C_out]
    float* __restrict__ out)
{
    __shared__ float lds[CI_CHUNK * 3 * PW_];  // 64*3*58*4 = 44544 B

    const int tid = threadIdx.x;
    const int nh  = blockIdx.x;          // n*56 + h
    const int n   = nh / H_;
    const int h   = nh % H_;
    const int co  = blockIdx.y * 64 + (tid & 63);
    const int wg  = tid >> 6;            // 0..3
    const int w0  = wg * 14;

    float acc[14];
#pragma unroll
    for (int i = 0; i < 14; ++i) acc[i] = 0.f;

    for (int c0 = 0; c0 < C_; c0 += CI_CHUNK) {
        __syncthreads();
        // Stage 3 input rows (h-1, h, h+1) for CI_CHUNK channels, zero-padded.
        // lds index = (ci_local*3 + r)*PW_ + pw ; lds[..][pw] = x[.., pw-1]
        for (int idx = tid; idx < CI_CHUNK * 3 * PW_; idx += 256) {
            int pw = idx % PW_;
            int rr = idx / PW_;
            int r  = rr % 3;
            int ci = c0 + rr / 3;
            int hs = h + r - 1;
            int ws = pw - 1;
            float v = 0.f;
            if ((unsigned)hs < (unsigned)H_ && (unsigned)ws < (unsigned)W_)
                v = in[(((size_t)n * C_ + ci) * H_ + hs) * W_ + ws];
            lds[idx] = v;
        }
        __syncthreads();

        for (int cl = 0; cl < CI_CHUNK; ++cl) {
            const int ci = c0 + cl;
            const float* wp = wt + ((size_t)co * C_ + ci) * 9;
            // prefetch the 9 weights for this (co, ci)
            float wr[9];
#pragma unroll
            for (int k = 0; k < 9; ++k) wr[k] = wp[k];
            const int base = cl * 3 * PW_;
#pragma unroll
            for (int r = 0; r < 3; ++r) {
                float xv[16];
#pragma unroll
                for (int j = 0; j < 16; ++j)
                    xv[j] = lds[base + r * PW_ + w0 + j];
                const float wa = wr[r * 3 + 0];
                const float wb = wr[r * 3 + 1];
                const float wc = wr[r * 3 + 2];
#pragma unroll
                for (int w = 0; w < 14; ++w)
                    acc[w] += xv[w] * wa + xv[w + 1] * wb + xv[w + 2] * wc;
            }
        }
    }

    const float m = mask[co];
    const size_t obase = (((size_t)n * C_ + co) * H_ + h) * W_ + w0;
#pragma unroll
    for (int w = 0; w < 14; ++w)
        out[obase + w] = acc[w] * m;
}

// Per-channel batch stats over (N,H,W); emits fused scale/shift:
//   y = x*scale[c] + shift[c]  ==  (x-mean)*rsqrt(var+eps)*gamma + beta
extern "C" __global__ __launch_bounds__(256) void bn_stats_kernel(
    const float* __restrict__ hbuf,
    const float* __restrict__ gamma,
    const float* __restrict__ beta,
    float* __restrict__ scale,
    float* __restrict__ shift)
{
    __shared__ float ssum[256];
    __shared__ float ssq[256];
    const int c = blockIdx.x;
    const int tid = threadIdx.x;
    float s = 0.f, q = 0.f;
    for (int n = 0; n < N_; ++n) {
        const float* p = hbuf + ((size_t)n * C_ + c) * HW_;
        for (int i = tid; i < HW_; i += 256) {
            float v = p[i];
            s += v;
            q += v * v;
        }
    }
    ssum[tid] = s; ssq[tid] = q;
    __syncthreads();
    for (int ofs = 128; ofs > 0; ofs >>= 1) {
        if (tid < ofs) {
            ssum[tid] += ssum[tid + ofs];
            ssq[tid]  += ssq[tid + ofs];
        }
        __syncthreads();
    }
    if (tid == 0) {
        const float inv_n = 1.f / (float)NHW_;
        float mean = ssum[0] * inv_n;
        float var  = ssq[0] * inv_n - mean * mean;
        var = fmaxf(var, 0.f);
        float inv = rsqrtf(var + 1e-5f);
        float sc = gamma[c] * inv;
        scale[c] = sc;
        shift[c] = beta[c] - mean * sc;
    }
}

// y = relu(x*scale + shift) ; one block per (n,c) plane. In-place safe.
extern "C" __global__ __launch_bounds__(256) void bn_relu_kernel(
    const float* __restrict__ hbuf,
    const float* __restrict__ scale,
    const float* __restrict__ shift,
    float* __restrict__ out)
{
    const int nc = blockIdx.x;
    const int c  = nc % C_;
    const float s = scale[c], b = shift[c];
    const size_t base = (size_t)nc * HW_;
    for (int i = threadIdx.x; i < HW_; i += 256) {
        float v = hbuf[base + i] * s + b;
        out[base + i] = fmaxf(v, 0.f);
    }
}

// y = relu(x*scale + shift + residual)
extern "C" __global__ __launch_bounds__(256) void bn_add_relu_kernel(
    const float* __restrict__ hbuf,
    const float* __restrict__ resid,
    const float* __restrict__ scale,
    const float* __restrict__ shift,
    float* __restrict__ out)
{
    const int nc = blockIdx.x;
    const int c  = nc % C_;
    const float s = scale[c], b = shift[c];
    const size_t base = (size_t)nc * HW_;
    for (int i = threadIdx.x; i < HW_; i += 256) {
        float v = hbuf[base + i] * s + b + resid[base + i];
        out[base + i] = fmaxf(v, 0.f);
    }
}

extern "C" void kernel_launch(void* const* d_in, const int* in_sizes, int n_in,
                              void* d_out, int out_size, void* d_ws, size_t ws_size,
                              hipStream_t stream) {
    // setup_inputs order: x, W1, W2, gamma1, beta1, gamma2, beta2, mask1, mask2
    const float* x      = (const float*)d_in[0];
    const float* W1     = (const float*)d_in[1];
    const float* W2     = (const float*)d_in[2];
    const float* gamma1 = (const float*)d_in[3];
    const float* beta1  = (const float*)d_in[4];
    const float* gamma2 = (const float*)d_in[5];
    const float* beta2  = (const float*)d_in[6];
    const float* mask1  = (const float*)d_in[7];
    const float* mask2  = (const float*)d_in[8];
    float* out = (float*)d_out;

    // Workspace: 4 KB of BN scale/shift + ONE fp32 tensor (h2 = 102.76 MB).
    // h1/h1n live in d_out (BN1+ReLU applied in place); final kernel
    // reads h2 + x and overwrites d_out.
    char* ws = (char*)d_ws;
    float* scale1 = (float*)ws;                 // 256 f32
    float* shift1 = scale1 + C_;
    float* scale2 = shift1 + C_;
    float* shift2 = scale2 + C_;
    float* h2 = (float*)(ws + 4096);

    dim3 cgrid(N_ * H_, C_ / 64);   // (1792, 4)
    dim3 cblock(256);

    // h1 = conv(x, W1) * mask1            -> d_out
    BasicBlock_4355096838467_kernel<<<cgrid, cblock, 0, stream>>>(x, W1, mask1, out);
    // BN1 stats
    bn_stats_kernel<<<dim3(C_), cblock, 0, stream>>>(out, gamma1, beta1, scale1, shift1);
    // h1n = relu(bn1(h1))                 -> d_out (in place)
    bn_relu_kernel<<<dim3(N_ * C_), cblock, 0, stream>>>(out, scale1, shift1, out);
    // h2 = conv(h1n, W2) * mask2          -> ws
    BasicBlock_4355096838467_kernel<<<cgrid, cblock, 0, stream>>>(out, W2, mask2, h2);
    // BN2 stats
    bn_stats_kernel<<<dim3(C_), cblock, 0, stream>>>(h2, gamma2, beta2, scale2, shift2);
    // out = relu(bn2(h2) + x)             -> d_out
    bn_add_relu_kernel<<<dim3(N_ * C_), cblock, 0, stream>>>(h2, x, scale2, shift2, out);
}

// Round 4
// 936.714 us; speedup vs baseline: 6.5718x; 6.5718x over previous
//
#include <hip/hip_runtime.h>

// BasicBlock: N=32, C=256, H=W=56, two 3x3 convs (stride 1, pad 1), channel
// masks, training-mode BN, residual+ReLU. fp32 I/O; convs run on bf16 MFMA
// (fp32 accumulate) — error budget ~0.05 vs 0.14375 threshold.
#define N_   32
#define C_   256
#define H_   56
#define W_   56
#define HW_  (H_ * W_)        // 3136
#define NHW_ (N_ * HW_)       // 100352
#define NPIX (N_ * HW_)       // pixels in NHWC tensor

typedef unsigned short u16;
typedef __attribute__((ext_vector_type(8))) short short8;   // 8 bf16 (A/B frag)
typedef __attribute__((ext_vector_type(4))) float f32x4;    // C/D frag

__device__ __forceinline__ float b2f(u16 u) {
    union { unsigned int i; float f; } v; v.i = ((unsigned int)u) << 16; return v.f;
}
__device__ __forceinline__ u16 f2b(float f) {
    union { float f; unsigned int i; } v; v.f = f;
    unsigned int r = v.i + 0x7fffu + ((v.i >> 16) & 1u);   // RNE
    return (u16)(r >> 16);
}

// ---------------------------------------------------------------------------
// x (fp32 NCHW) -> xb (bf16 NHWC). Block = (n,h); LDS transpose, pad 57.
extern "C" __global__ __launch_bounds__(256) void cvt_x_kernel(
    const float* __restrict__ x, u16* __restrict__ xb)
{
    __shared__ float t[64 * 57];
    const int nh = blockIdx.x, n = nh / H_, h = nh % H_;
    for (int cb = 0; cb < 4; ++cb) {
        __syncthreads();
        for (int idx = threadIdx.x; idx < 64 * 56; idx += 256) {
            int cc = idx / 56, w = idx % 56;
            t[cc * 57 + w] = x[(((size_t)(n * C_ + cb * 64 + cc)) * H_ + h) * W_ + w];
        }
        __syncthreads();
        for (int idx = threadIdx.x; idx < 56 * 64; idx += 256) {
            int w = idx >> 6, cc = idx & 63;
            xb[(((size_t)(n * H_ + h) * W_) + w) * C_ + cb * 64 + cc] = f2b(t[cc * 57 + w]);
        }
    }
}

// ---------------------------------------------------------------------------
// W [co][ci][3][3] fp32 -> Wp [rs][co][ci] bf16. 589824 elems, grid 2304.
extern "C" __global__ __launch_bounds__(256) void pack_w_kernel(
    const float* __restrict__ w, u16* __restrict__ wp)
{
    int idx = blockIdx.x * 256 + threadIdx.x;
    int rs = idx >> 16;
    int co = (idx >> 8) & 255, ci = idx & 255;
    wp[idx] = f2b(w[((size_t)(co * C_ + ci)) * 9 + rs]);
}

// ---------------------------------------------------------------------------
// Implicit-GEMM 3x3 conv on MFMA. Grid (896, 2): x = n*28 + hb (2-row pair),
// y = co block of 128. Block 256 thr = 4 waves (2 co-halves x 2 rows).
// Wave tile: 64 co x 64 px (one row, 56 valid) as 4x4 mfma 16x16x32 grid.
// LDS: [4 halo rows][68 slots][64 ci] bf16, 16B octs XOR-swizzled by slot.
extern "C" __global__ __launch_bounds__(256, 2) void BasicBlock_4355096838467_kernel(
    const u16* __restrict__ xb,    // [N][56][56][256] bf16
    const u16* __restrict__ wp,    // [9][256][256] bf16
    const float* __restrict__ mask,
    u16* __restrict__ outb)        // [N][56][56][256] bf16
{
    __shared__ u16 lds[4 * 68 * 64];   // 34816 B

    const int tid  = threadIdx.x;
    const int wave = tid >> 6, lane = tid & 63;
    const int l15  = lane & 15, lq = lane >> 4;
    const int wave_co = wave >> 1, wave_px = wave & 1;
    const int bpx = blockIdx.x;
    const int n = bpx / 28, hb = bpx % 28;
    const int h0 = hb * 2;
    const int co_blk = blockIdx.y;

    f32x4 acc[4][4];
#pragma unroll
    for (int i = 0; i < 4; ++i)
#pragma unroll
        for (int j = 0; j < 4; ++j) acc[i][j] = (f32x4){0.f, 0.f, 0.f, 0.f};

    const int co_wave = co_blk * 128 + wave_co * 64;

    for (int c0 = 0; c0 < C_; c0 += 64) {
        __syncthreads();
        // stage 4 halo rows x 58 slots x 64 ci (8 octs of 16B), zero-padded
        for (int it = tid; it < 4 * 58 * 8; it += 256) {
            int oct = it & 7, t = it >> 3;
            int slot = t % 58, rr = t / 58;
            int row = h0 - 1 + rr, col = slot - 1;
            short8 v = (short8){0, 0, 0, 0, 0, 0, 0, 0};
            if ((unsigned)row < (unsigned)H_ && (unsigned)col < (unsigned)W_)
                v = *(const short8*)(xb + (((size_t)(n * H_ + row) * W_ + col) << 8) + c0 + oct * 8);
            int so = oct ^ (slot & 7);
            *(short8*)(lds + ((rr * 68 + slot) * 8 + so) * 8) = v;
        }
        __syncthreads();

#pragma unroll
        for (int r = 0; r < 3; ++r)
#pragma unroll
        for (int s = 0; s < 3; ++s)
#pragma unroll
        for (int kk = 0; kk < 2; ++kk) {
            const int rs = r * 3 + s;
            short8 af[4];
#pragma unroll
            for (int fm = 0; fm < 4; ++fm) {
                int co = co_wave + fm * 16 + l15;
                int ci = c0 + kk * 32 + lq * 8;
                af[fm] = *(const short8*)(wp + ((size_t)(rs * C_ + co) << 8) + ci);
            }
            short8 bf[4];
#pragma unroll
            for (int fn = 0; fn < 4; ++fn) {
                int slot = fn * 16 + l15 + s;
                int oct  = kk * 4 + lq;
                int so   = oct ^ (slot & 7);
                bf[fn] = *(const short8*)(lds + (((wave_px + r) * 68 + slot) * 8 + so) * 8);
            }
#pragma unroll
            for (int fm = 0; fm < 4; ++fm)
#pragma unroll
            for (int fn = 0; fn < 4; ++fn)
                acc[fm][fn] = __builtin_amdgcn_mfma_f32_16x16x32_bf16(
                    af[fm], bf[fn], acc[fm][fn], 0, 0, 0);
        }
    }

    // epilogue: C/D layout col=lane&15 (pixel), row=lq*4+reg (co). mask folded.
    const int row = h0 + wave_px;
#pragma unroll
    for (int fn = 0; fn < 4; ++fn) {
        int px = fn * 16 + l15;
        if (px < W_) {
#pragma unroll
            for (int fm = 0; fm < 4; ++fm) {
                int co_b = co_wave + fm * 16 + lq * 4;
                const f32x4 mk = *(const f32x4*)(mask + co_b);
                size_t base = (((size_t)(n * H_ + row) * W_ + px) << 8) + co_b;
                ushort4 o;
                o.x = f2b(acc[fm][fn][0] * mk[0]);
                o.y = f2b(acc[fm][fn][1] * mk[1]);
                o.z = f2b(acc[fm][fn][2] * mk[2]);
                o.w = f2b(acc[fm][fn][3] * mk[3]);
                *(ushort4*)(outb + base) = o;
            }
        }
    }
}

// ---------------------------------------------------------------------------
// zero 1024 floats (gsum1,gsq1,gsum2,gsq2). grid 4 x 256.
extern "C" __global__ void zero_accum_kernel(float* __restrict__ p) {
    p[blockIdx.x * 256 + threadIdx.x] = 0.f;
}

// Per-channel sum/sumsq over NHWC bf16 via block partials + atomics. grid 392.
extern "C" __global__ __launch_bounds__(256) void stats_nhwc_kernel(
    const u16* __restrict__ hb, float* __restrict__ gsum, float* __restrict__ gsq)
{
    __shared__ float s_s[8 * 256];
    __shared__ float s_q[8 * 256];
    const int g = threadIdx.x >> 5, l = threadIdx.x & 31;
    float s[8], q[8];
#pragma unroll
    for (int j = 0; j < 8; ++j) { s[j] = 0.f; q[j] = 0.f; }
    const int pbase = blockIdx.x * 256;
    for (int t = 0; t < 32; ++t) {
        int p = pbase + g + t * 8;
        short8 v = *(const short8*)(hb + (size_t)p * C_ + l * 8);
#pragma unroll
        for (int j = 0; j < 8; ++j) {
            float f = b2f((u16)v[j]);
            s[j] += f; q[j] += f * f;
        }
    }
#pragma unroll
    for (int j = 0; j < 8; ++j) {
        s_s[g * 256 + l * 8 + j] = s[j];
        s_q[g * 256 + l * 8 + j] = q[j];
    }
    __syncthreads();
    const int c = threadIdx.x;
    float S = 0.f, Q = 0.f;
#pragma unroll
    for (int g2 = 0; g2 < 8; ++g2) { S += s_s[g2 * 256 + c]; Q += s_q[g2 * 256 + c]; }
    atomicAdd(&gsum[c], S);
    atomicAdd(&gsq[c], Q);
}

// scale/shift from accumulated stats. 1 block x 256.
extern "C" __global__ void finalize_bn_kernel(
    const float* __restrict__ gsum, const float* __restrict__ gsq,
    const float* __restrict__ gamma, const float* __restrict__ beta,
    float* __restrict__ scale, float* __restrict__ shift)
{
    const int c = threadIdx.x;
    const float inv_n = 1.f / (float)NHW_;
    float mean = gsum[c] * inv_n;
    float var  = gsq[c] * inv_n - mean * mean;
    var = fmaxf(var, 0.f);
    float inv = rsqrtf(var + 1e-5f);
    float sc = gamma[c] * inv;
    scale[c] = sc;
    shift[c] = beta[c] - mean * sc;
}

// In-place BN+ReLU on NHWC bf16. grid 12544, 8 elems/thread.
extern "C" __global__ __launch_bounds__(256) void bn_relu_nhwc_kernel(
    u16* __restrict__ hb, const float* __restrict__ scale, const float* __restrict__ shift)
{
    size_t idx = ((size_t)blockIdx.x * 256 + threadIdx.x) * 8;
    int c0 = (int)(idx & 255);
    short8 v = *(short8*)(hb + idx);
    short8 o;
#pragma unroll
    for (int j = 0; j < 8; ++j) {
        int c = c0 + j;
        float f = b2f((u16)v[j]) * scale[c] + shift[c];
        o[j] = (short)f2b(fmaxf(f, 0.f));
    }
    *(short8*)(hb + idx) = o;
}

// out = relu(bn2(h2) + x): NHWC bf16 -> NCHW fp32 via LDS transpose. grid (n,h).
extern "C" __global__ __launch_bounds__(256) void bn_add_relu_out_kernel(
    const u16* __restrict__ h2b, const float* __restrict__ x,
    const float* __restrict__ scale, const float* __restrict__ shift,
    float* __restrict__ out)
{
    __shared__ float t[64 * 57];
    const int nh = blockIdx.x, n = nh / H_, h = nh % H_;
    const size_t pixbase = ((size_t)(n * H_ + h) * W_) << 8;
    for (int cb = 0; cb < 4; ++cb) {
        __syncthreads();
        for (int it = threadIdx.x; it < 448; it += 256) {      // 56 px * 8 octs
            int w = it >> 3, oc = it & 7;
            short8 v = *(const short8*)(h2b + pixbase + ((size_t)w << 8) + cb * 64 + oc * 8);
#pragma unroll
            for (int j = 0; j < 8; ++j) t[(oc * 8 + j) * 57 + w] = b2f((u16)v[j]);
        }
        __syncthreads();
        for (int it = threadIdx.x; it < 64 * 56; it += 256) {
            int cl = it / 56, w = it % 56;
            int c = cb * 64 + cl;
            size_t oidx = ((size_t)(n * C_ + c) * H_ + h) * W_ + w;
            float v = t[cl * 57 + w] * scale[c] + shift[c] + x[oidx];
            out[oidx] = fmaxf(v, 0.f);
        }
    }
}

// ---------------------------------------------------------------------------
extern "C" void kernel_launch(void* const* d_in, const int* in_sizes, int n_in,
                              void* d_out, int out_size, void* d_ws, size_t ws_size,
                              hipStream_t stream) {
    const float* x      = (const float*)d_in[0];
    const float* W1     = (const float*)d_in[1];
    const float* W2     = (const float*)d_in[2];
    const float* gamma1 = (const float*)d_in[3];
    const float* beta1  = (const float*)d_in[4];
    const float* gamma2 = (const float*)d_in[5];
    const float* beta2  = (const float*)d_in[6];
    const float* mask1  = (const float*)d_in[7];
    const float* mask2  = (const float*)d_in[8];
    float* out = (float*)d_out;

    // workspace: stats/scales (8 KB) | Wp1 | Wp2 | xb (51.4 MB, reused as h2b)
    char* ws = (char*)d_ws;
    float* gsum1  = (float*)ws;            // 256
    float* gsq1   = gsum1 + 256;
    float* gsum2  = gsq1 + 256;
    float* gsq2   = gsum2 + 256;
    float* scale1 = gsq2 + 256;
    float* shift1 = scale1 + 256;
    float* scale2 = shift1 + 256;
    float* shift2 = scale2 + 256;
    u16* Wp1 = (u16*)(ws + 8192);
    u16* Wp2 = Wp1 + 9 * 256 * 256;
    u16* xb  = Wp2 + 9 * 256 * 256;        // 25,690,112 u16
    u16* h2b = xb;                          // xb dead after conv1
    u16* h1b = (u16*)d_out;                 // 51.4 MB inside the 411 MB output

    zero_accum_kernel<<<dim3(4), dim3(256), 0, stream>>>(gsum1);
    cvt_x_kernel<<<dim3(N_ * H_), dim3(256), 0, stream>>>(x, xb);
    pack_w_kernel<<<dim3(2304), dim3(256), 0, stream>>>(W1, Wp1);
    pack_w_kernel<<<dim3(2304), dim3(256), 0, stream>>>(W2, Wp2);

    dim3 cgrid(N_ * 28, 2);
    BasicBlock_4355096838467_kernel<<<cgrid, dim3(256), 0, stream>>>(xb, Wp1, mask1, h1b);
    stats_nhwc_kernel<<<dim3(392), dim3(256), 0, stream>>>(h1b, gsum1, gsq1);
    finalize_bn_kernel<<<dim3(1), dim3(256), 0, stream>>>(gsum1, gsq1, gamma1, beta1, scale1, shift1);
    bn_relu_nhwc_kernel<<<dim3(12544), dim3(256), 0, stream>>>(h1b, scale1, shift1);

    BasicBlock_4355096838467_kernel<<<cgrid, dim3(256), 0, stream>>>(h1b, Wp2, mask2, h2b);
    stats_nhwc_kernel<<<dim3(392), dim3(256), 0, stream>>>(h2b, gsum2, gsq2);
    finalize_bn_kernel<<<dim3(1), dim3(256), 0, stream>>>(gsum2, gsq2, gamma2, beta2, scale2, shift2);
    bn_add_relu_out_kernel<<<dim3(N_ * H_), dim3(256), 0, stream>>>(h2b, x, scale2, shift2, out);
}

// Round 6
// 932.033 us; speedup vs baseline: 6.6048x; 1.0050x over previous
//
#include <hip/hip_runtime.h>

// BasicBlock: N=32, C=256, H=W=56, two 3x3 convs (stride 1, pad 1), channel
// masks, training-mode BN, residual+ReLU. fp32 I/O; convs on bf16 MFMA.
#define N_   32
#define C_   256
#define H_   56
#define W_   56
#define HW_  (H_ * W_)        // 3136
#define NHW_ (N_ * HW_)       // 100352

typedef unsigned short u16;
typedef __attribute__((ext_vector_type(8))) short short8;   // 8 bf16
typedef __attribute__((ext_vector_type(4))) float f32x4;

__device__ __forceinline__ float b2f(u16 u) {
    union { unsigned int i; float f; } v; v.i = ((unsigned int)u) << 16; return v.f;
}
__device__ __forceinline__ u16 f2b(float f) {
    union { float f; unsigned int i; } v; v.f = f;
    unsigned int r = v.i + 0x7fffu + ((v.i >> 16) & 1u);   // RNE
    return (u16)(r >> 16);
}

typedef const __attribute__((address_space(1))) unsigned int* as1_u32p;
typedef __attribute__((address_space(3))) unsigned int* as3_u32p;
__device__ __forceinline__ void gload_lds16(const u16* g, u16* l) {
    __builtin_amdgcn_global_load_lds((as1_u32p)g, (as3_u32p)l, 16, 0, 0);
}

// ---------------------------------------------------------------------------
// x (fp32 NCHW) -> xb (bf16 NHWC). Block = (n,h); LDS transpose, pad 57.
extern "C" __global__ __launch_bounds__(256) void cvt_x_kernel(
    const float* __restrict__ x, u16* __restrict__ xb)
{
    __shared__ float t[64 * 57];
    const int nh = blockIdx.x, n = nh / H_, h = nh % H_;
    for (int cb = 0; cb < 4; ++cb) {
        __syncthreads();
        for (int idx = threadIdx.x; idx < 64 * 56; idx += 256) {
            int cc = idx / 56, w = idx % 56;
            t[cc * 57 + w] = x[(((size_t)(n * C_ + cb * 64 + cc)) * H_ + h) * W_ + w];
        }
        __syncthreads();
        for (int idx = threadIdx.x; idx < 56 * 64; idx += 256) {
            int w = idx >> 6, cc = idx & 63;
            xb[(((size_t)(n * H_ + h) * W_) + w) * C_ + cb * 64 + cc] = f2b(t[cc * 57 + w]);
        }
    }
}

// ---------------------------------------------------------------------------
// W [co][ci][3][3] fp32 -> wpA [rs][cih 8][cog 16][l15 16][lq 4][j 8] bf16.
// A wave's A-frag load for (rs, ci-half, cog) is then 1 KB fully contiguous.
extern "C" __global__ __launch_bounds__(256) void pack_w_kernel(
    const float* __restrict__ w, u16* __restrict__ wp)
{
    int o = blockIdx.x * 256 + threadIdx.x;      // grid 2304 -> 589824
    int j = o & 7, lq = (o >> 3) & 3, l15 = (o >> 5) & 15;
    int cog = (o >> 9) & 15, cih = (o >> 13) & 7, rs = o >> 16;
    int co = cog * 16 + l15;
    int ci = cih * 32 + lq * 8 + j;
    wp[o] = f2b(w[((size_t)co * C_ + ci) * 9 + rs]);
}

// ---------------------------------------------------------------------------
// Implicit-GEMM 3x3 conv on MFMA. Grid (896, 2): x = n*28 + hb (2-row pair),
// y = 128-co block. 4 waves: wave>>1 = co half, wave&1 = output row.
// Wave tile 64co x 64px = 4x4 grid of mfma_f32_16x16x32_bf16.
// LDS: 240 pixel-slots x 64 ci bf16 ([rr<4][slot<58] + slack), 16B octs
// XOR-swizzled by slot; staged via global_load_lds with the swizzle baked
// into each lane's GLOBAL address (LDS dest is wave-uniform base + lane*16).
// Halo/OOB lanes read from a DEDICATED zeroed scratch (must overlap nothing —
// round-5 bug: it aliased BN scale/shift, whose fp32 bit patterns read as
// bf16 included inf/NaN). A-frags prefetched 2 steps deep from packed wpA.
extern "C" __global__ __launch_bounds__(256, 3) void BasicBlock_4355096838467_kernel(
    const u16* __restrict__ xb,     // [N][56][56][256] bf16
    const u16* __restrict__ wpA,    // packed weights
    const float* __restrict__ mask,
    const u16* __restrict__ zeropad,
    u16* __restrict__ outb)         // [N][56][56][256] bf16
{
    __shared__ u16 lds[240 * 64];   // 30720 B

    const int tid  = threadIdx.x;
    const int wave = tid >> 6, lane = tid & 63;
    const int l15  = lane & 15, lq = lane >> 4;
    const int wave_co = wave >> 1, wave_px = wave & 1;
    const int n = blockIdx.x / 28, hb = blockIdx.x % 28;
    const int h0 = hb * 2;
    const int cog_base = blockIdx.y * 8 + wave_co * 4;
    const size_t abase0 = (size_t)cog_base * 512 + (size_t)(l15 * 32 + lq * 8);

    f32x4 acc[4][4];
#pragma unroll
    for (int i = 0; i < 4; ++i)
#pragma unroll
        for (int j = 0; j < 4; ++j) acc[i][j] = (f32x4){0.f, 0.f, 0.f, 0.f};

    for (int cc = 0; cc < 4; ++cc) {
        const int c0 = cc * 64;
        __syncthreads();
        // stage 232 pixel-rows (4 halo rows x 58 slots) x 64 ci = 29 KB
        for (int is = wave; is < 29; is += 4) {
            int L = is * 64 + lane;           // lane-slot 0..1855
            int pixel = L >> 3, so = L & 7;   // LDS layout index
            int rr = pixel / 58, slot = pixel - rr * 58;
            int oct = so ^ (slot & 7);        // global oct for this LDS slot
            int row = h0 - 1 + rr, col = slot - 1;
            const u16* gp = ((unsigned)row < (unsigned)H_ && (unsigned)col < (unsigned)W_)
                ? xb + (((size_t)(n * H_ + row) * W_ + col) << 8) + c0 + oct * 8
                : zeropad + oct * 8;
            gload_lds16(gp, lds + is * 512);
        }
        __syncthreads();

        // 18 K-steps: t -> rs = t>>1 (r*3+s), kk = t&1 (ci half of 32)
        short8 afq[3][4];
        auto loadA = [&](int t, short8 dst[4]) {
            const int rs = t >> 1, kk = t & 1;
            const size_t b = (size_t)rs * 65536 + (size_t)(cc * 2 + kk) * 8192 + abase0;
#pragma unroll
            for (int fm = 0; fm < 4; ++fm)
                dst[fm] = *(const short8*)(wpA + b + (size_t)fm * 512);
        };
        loadA(0, afq[0]);
        loadA(1, afq[1]);
#pragma unroll
        for (int t = 0; t < 18; ++t) {
            if (t + 2 < 18) loadA(t + 2, afq[(t + 2) % 3]);
            const int rs = t >> 1, kk = t & 1;
            const int r = rs / 3, s = rs - r * 3;
            short8 bf[4];
#pragma unroll
            for (int fn = 0; fn < 4; ++fn) {
                int slot = fn * 16 + l15 + s;
                int pixel = (wave_px + r) * 58 + slot;
                int so = (kk * 4 + lq) ^ (slot & 7);
                bf[fn] = *(const short8*)(lds + pixel * 64 + so * 8);
            }
#pragma unroll
            for (int fm = 0; fm < 4; ++fm)
#pragma unroll
                for (int fn = 0; fn < 4; ++fn)
                    acc[fm][fn] = __builtin_amdgcn_mfma_f32_16x16x32_bf16(
                        afq[t % 3][fm], bf[fn], acc[fm][fn], 0, 0, 0);
        }
    }

    // epilogue: C/D col=lane&15 (pixel), row=lq*4+reg (co). mask folded.
    const int row = h0 + wave_px;
#pragma unroll
    for (int fn = 0; fn < 4; ++fn) {
        int px = fn * 16 + l15;
        if (px < W_) {
#pragma unroll
            for (int fm = 0; fm < 4; ++fm) {
                int co_b = cog_base * 16 + fm * 16 + lq * 4;
                const f32x4 mk = *(const f32x4*)(mask + co_b);
                size_t base = (((size_t)(n * H_ + row) * W_ + px) << 8) + co_b;
                ushort4 o;
                o.x = f2b(acc[fm][fn][0] * mk[0]);
                o.y = f2b(acc[fm][fn][1] * mk[1]);
                o.z = f2b(acc[fm][fn][2] * mk[2]);
                o.w = f2b(acc[fm][fn][3] * mk[3]);
                *(ushort4*)(outb + base) = o;
            }
        }
    }
}

// ---------------------------------------------------------------------------
// zero stats accumulators + scale/shift + zeropad scratch (12 KB). grid 12.
extern "C" __global__ void zero_accum_kernel(float* __restrict__ p) {
    p[blockIdx.x * 256 + threadIdx.x] = 0.f;
}

// Per-channel sum/sumsq over NHWC bf16 via block partials + atomics. grid 392.
extern "C" __global__ __launch_bounds__(256) void stats_nhwc_kernel(
    const u16* __restrict__ hb, float* __restrict__ gsum, float* __restrict__ gsq)
{
    __shared__ float s_s[8 * 256];
    __shared__ float s_q[8 * 256];
    const int g = threadIdx.x >> 5, l = threadIdx.x & 31;
    float s[8], q[8];
#pragma unroll
    for (int j = 0; j < 8; ++j) { s[j] = 0.f; q[j] = 0.f; }
    const int pbase = blockIdx.x * 256;
    for (int t = 0; t < 32; ++t) {
        int p = pbase + g + t * 8;
        short8 v = *(const short8*)(hb + (size_t)p * C_ + l * 8);
#pragma unroll
        for (int j = 0; j < 8; ++j) {
            float f = b2f((u16)v[j]);
            s[j] += f; q[j] += f * f;
        }
    }
#pragma unroll
    for (int j = 0; j < 8; ++j) {
        s_s[g * 256 + l * 8 + j] = s[j];
        s_q[g * 256 + l * 8 + j] = q[j];
    }
    __syncthreads();
    const int c = threadIdx.x;
    float S = 0.f, Q = 0.f;
#pragma unroll
    for (int g2 = 0; g2 < 8; ++g2) { S += s_s[g2 * 256 + c]; Q += s_q[g2 * 256 + c]; }
    atomicAdd(&gsum[c], S);
    atomicAdd(&gsq[c], Q);
}

// scale/shift from accumulated stats. 1 block x 256.
extern "C" __global__ void finalize_bn_kernel(
    const float* __restrict__ gsum, const float* __restrict__ gsq,
    const float* __restrict__ gamma, const float* __restrict__ beta,
    float* __restrict__ scale, float* __restrict__ shift)
{
    const int c = threadIdx.x;
    const float inv_n = 1.f / (float)NHW_;
    float mean = gsum[c] * inv_n;
    float var  = gsq[c] * inv_n - mean * mean;
    var = fmaxf(var, 0.f);
    float inv = rsqrtf(var + 1e-5f);
    float sc = gamma[c] * inv;
    scale[c] = sc;
    shift[c] = beta[c] - mean * sc;
}

// In-place BN+ReLU on NHWC bf16. grid 12544, 8 elems/thread.
extern "C" __global__ __launch_bounds__(256) void bn_relu_nhwc_kernel(
    u16* __restrict__ hb, const float* __restrict__ scale, const float* __restrict__ shift)
{
    size_t idx = ((size_t)blockIdx.x * 256 + threadIdx.x) * 8;
    int c0 = (int)(idx & 255);
    short8 v = *(short8*)(hb + idx);
    short8 o;
#pragma unroll
    for (int j = 0; j < 8; ++j) {
        int c = c0 + j;
        float f = b2f((u16)v[j]) * scale[c] + shift[c];
        o[j] = (short)f2b(fmaxf(f, 0.f));
    }
    *(short8*)(hb + idx) = o;
}

// out = relu(bn2(h2) + x): NHWC bf16 -> NCHW fp32 via LDS transpose. grid (n,h).
extern "C" __global__ __launch_bounds__(256) void bn_add_relu_out_kernel(
    const u16* __restrict__ h2b, const float* __restrict__ x,
    const float* __restrict__ scale, const float* __restrict__ shift,
    float* __restrict__ out)
{
    __shared__ float t[64 * 57];
    const int nh = blockIdx.x, n = nh / H_, h = nh % H_;
    const size_t pixbase = ((size_t)(n * H_ + h) * W_) << 8;
    for (int cb = 0; cb < 4; ++cb) {
        __syncthreads();
        for (int it = threadIdx.x; it < 448; it += 256) {      // 56 px * 8 octs
            int w = it >> 3, oc = it & 7;
            short8 v = *(const short8*)(h2b + pixbase + ((size_t)w << 8) + cb * 64 + oc * 8);
#pragma unroll
            for (int j = 0; j < 8; ++j) t[(oc * 8 + j) * 57 + w] = b2f((u16)v[j]);
        }
        __syncthreads();
        for (int it = threadIdx.x; it < 64 * 56; it += 256) {
            int cl = it / 56, w = it % 56;
            int c = cb * 64 + cl;
            size_t oidx = ((size_t)(n * C_ + c) * H_ + h) * W_ + w;
            float v = t[cl * 57 + w] * scale[c] + shift[c] + x[oidx];
            out[oidx] = fmaxf(v, 0.f);
        }
    }
}

// ---------------------------------------------------------------------------
extern "C" void kernel_launch(void* const* d_in, const int* in_sizes, int n_in,
                              void* d_out, int out_size, void* d_ws, size_t ws_size,
                              hipStream_t stream) {
    const float* x      = (const float*)d_in[0];
    const float* W1     = (const float*)d_in[1];
    const float* W2     = (const float*)d_in[2];
    const float* gamma1 = (const float*)d_in[3];
    const float* beta1  = (const float*)d_in[4];
    const float* gamma2 = (const float*)d_in[5];
    const float* beta2  = (const float*)d_in[6];
    const float* mask1  = (const float*)d_in[7];
    const float* mask2  = (const float*)d_in[8];
    float* out = (float*)d_out;

    // ws layout (NO overlaps — round-5 bug was zeropad aliasing scale/shift):
    // [0,4K)   stats accumulators (gsum1,gsq1,gsum2,gsq2)
    // [4K,8K)  scale1,shift1,scale2,shift2
    // [8K,12K) zeropad scratch (zeroed every launch, read-only thereafter)
    // [12K,..) Wp1 | Wp2 | xb (reused as h2b)
    char* ws = (char*)d_ws;
    float* gsum1  = (float*)ws;
    float* gsq1   = gsum1 + 256;
    float* gsum2  = gsq1 + 256;
    float* gsq2   = gsum2 + 256;
    float* scale1 = gsq2 + 256;
    float* shift1 = scale1 + 256;
    float* scale2 = shift1 + 256;
    float* shift2 = scale2 + 256;
    u16* zeropad = (u16*)(ws + 8192);
    u16* Wp1 = (u16*)(ws + 12288);
    u16* Wp2 = Wp1 + 9 * 256 * 256;
    u16* xb  = Wp2 + 9 * 256 * 256;
    u16* h2b = xb;                          // xb dead after conv1
    u16* h1b = (u16*)d_out;                 // bf16 scratch inside 102.8 MB output

    zero_accum_kernel<<<dim3(12), dim3(256), 0, stream>>>(gsum1);  // stats+scales+zeropad
    cvt_x_kernel<<<dim3(N_ * H_), dim3(256), 0, stream>>>(x, xb);
    pack_w_kernel<<<dim3(2304), dim3(256), 0, stream>>>(W1, Wp1);
    pack_w_kernel<<<dim3(2304), dim3(256), 0, stream>>>(W2, Wp2);

    dim3 cgrid(N_ * 28, 2);
    BasicBlock_4355096838467_kernel<<<cgrid, dim3(256), 0, stream>>>(xb, Wp1, mask1, zeropad, h1b);
    stats_nhwc_kernel<<<dim3(392), dim3(256), 0, stream>>>(h1b, gsum1, gsq1);
    finalize_bn_kernel<<<dim3(1), dim3(256), 0, stream>>>(gsum1, gsq1, gamma1, beta1, scale1, shift1);
    bn_relu_nhwc_kernel<<<dim3(12544), dim3(256), 0, stream>>>(h1b, scale1, shift1);

    BasicBlock_4355096838467_kernel<<<cgrid, dim3(256), 0, stream>>>(h1b, Wp2, mask2, zeropad, h2b);
    stats_nhwc_kernel<<<dim3(392), dim3(256), 0, stream>>>(h2b, gsum2, gsq2);
    finalize_bn_kernel<<<dim3(1), dim3(256), 0, stream>>>(gsum2, gsq2, gamma2, beta2, scale2, shift2);
    bn_add_relu_out_kernel<<<dim3(N_ * H_), dim3(256), 0, stream>>>(h2b, x, scale2, shift2, out);
}